// Round 13
// baseline (417.139 us; speedup 1.0000x reference)
//
#include <hip/hip_runtime.h>
#include <hip/hip_bf16.h>

#define NN 50000
#define NE 800000
#define CI 64
#define CO 128
#define NB 196     // ceil(NN/256) buckets of 256 nodes
#define CHUNK 2048 // edges per bin block
#define NCH 391    // ceil(NE/CHUNK)

typedef __attribute__((ext_vector_type(8))) short bf16x8;
typedef __attribute__((ext_vector_type(4))) float f32x4;

__device__ __forceinline__ unsigned short f2bf(float f) {
  unsigned int u = __float_as_uint(f);
  u += 0x7fffu + ((u >> 16) & 1u);   // RNE; inputs are finite
  return (unsigned short)(u >> 16);
}
__device__ __forceinline__ float bf2f_lo(unsigned int p) { return __uint_as_float(p << 16); }
__device__ __forceinline__ float bf2f_hi(unsigned int p) { return __uint_as_float(p & 0xffff0000u); }
__device__ __forceinline__ unsigned int pk2(float lo, float hi) {
  return ((unsigned int)f2bf(hi) << 16) | (unsigned int)f2bf(lo);
}

// ---------------- binned CSR build ----------------
// Round-13: bscan folded into bhist via last-block pattern (saves a launch).
__global__ __launch_bounds__(256) void k_bhist(const int* __restrict__ dst,
                                               int* __restrict__ bcnt,
                                               int* __restrict__ bkt_off,
                                               int* __restrict__ bkt_cur,
                                               int* __restrict__ done) {
  __shared__ int lc[NB];
  __shared__ int lastblk;
  int tid = threadIdx.x;
  for (int t = tid; t < NB; t += 256) lc[t] = 0;
  __syncthreads();
  int base = blockIdx.x * CHUNK;
#pragma unroll
  for (int i = 0; i < 8; ++i) {
    int idx = base + i * 256 + tid;
    if (idx < NE) atomicAdd(&lc[dst[idx] >> 8], 1);
  }
  __syncthreads();
  for (int t = tid; t < NB; t += 256) if (lc[t]) atomicAdd(&bcnt[t], lc[t]);
  // last block performs the bucket scan (all other blocks exit -> no deadlock)
  __threadfence();
  __syncthreads();
  if (tid == 0) lastblk = (atomicAdd(done, 1) == NCH - 1);
  __syncthreads();
  if (!lastblk) return;
  __threadfence();
  __shared__ int s[256];
  int t = tid;
  int v = (t < NB) ? atomicAdd(&bcnt[t], 0) : 0;   // coherent read
  s[t] = v;
  __syncthreads();
  for (int off = 1; off < 256; off <<= 1) {
    int x = (t >= off) ? s[t - off] : 0;
    __syncthreads();
    s[t] += x;
    __syncthreads();
  }
  if (t < NB) { int e = s[t] - v; bkt_off[t] = e; bkt_cur[t] = e; }
  if (t == 0) bkt_off[NB] = NE;
}

// Round-13: pairs packed to uint32 = (src<<8) | (dst&255)  (src<2^17, 25 bits)
__global__ __launch_bounds__(256) void k_bin(const int* __restrict__ src,
                                             const int* __restrict__ dst,
                                             int* __restrict__ bkt_cur,
                                             unsigned* __restrict__ pairs) {
  __shared__ int lcnt[NB];
  __shared__ int lbase[NB];
  int tid = threadIdx.x;
  for (int t = tid; t < NB; t += 256) lcnt[t] = 0;
  __syncthreads();
  int base = blockIdx.x * CHUNK;
  int ds[8], sr[8], rk[8];
#pragma unroll
  for (int i = 0; i < 8; ++i) {
    int idx = base + i * 256 + tid;
    if (idx < NE) {
      ds[i] = dst[idx]; sr[i] = src[idx];
      rk[i] = atomicAdd(&lcnt[ds[i] >> 8], 1);
    } else ds[i] = -1;
  }
  __syncthreads();
  for (int t = tid; t < NB; t += 256)
    lbase[t] = lcnt[t] ? atomicAdd(&bkt_cur[t], lcnt[t]) : 0;
  __syncthreads();
#pragma unroll
  for (int i = 0; i < 8; ++i) {
    if (ds[i] >= 0)
      pairs[lbase[ds[i] >> 8] + rk[i]] =
          ((unsigned)sr[i] << 8) | (unsigned)(ds[i] & 255);
  }
}

// Merged: per-bucket histogram -> LDS scan -> row_off -> ssrc fill.
__global__ __launch_bounds__(256) void k_fillB(const unsigned* __restrict__ pairs,
                                               const int* __restrict__ bkt_off,
                                               int* __restrict__ row_off,
                                               int* __restrict__ ssrc) {
  __shared__ int lc[256];
  __shared__ int ls[256];
  int t = threadIdx.x, b = blockIdx.x;
  lc[t] = 0;
  __syncthreads();
  int beg = bkt_off[b], end = bkt_off[b + 1];
  for (int i = beg + t; i < end; i += 256)
    atomicAdd(&lc[pairs[i] & 255], 1);
  __syncthreads();
  int v = lc[t];
  ls[t] = v;
  __syncthreads();
  for (int off = 1; off < 256; off <<= 1) {
    int x = (t >= off) ? ls[t - off] : 0;
    __syncthreads();
    ls[t] += x;
    __syncthreads();
  }
  int excl = ls[t] - v;
  int node = (b << 8) + t;
  if (node < NN) row_off[node] = beg + excl;
  if (b == 0 && t == 0) row_off[NN] = NE;
  lc[t] = beg + excl;          // reuse as global-position cursor
  __syncthreads();
  for (int i = beg + t; i < end; i += 256) {
    unsigned e = pairs[i];
    int pos = atomicAdd(&lc[e & 255], 1);
    ssrc[pos] = (int)(e >> 8);
  }
}

// ---------------- bf16 conversions (weights + u0 fused) ----------------
__global__ __launch_bounds__(256) void k_cvt(const float* __restrict__ w1,
    const float* __restrict__ m1, const float* __restrict__ m2,
    const float* __restrict__ m3, unsigned short* __restrict__ wb,
    const float* __restrict__ u0, unsigned short* __restrict__ ub) {
  int i = blockIdx.x * 256 + threadIdx.x;
  if (i < 14336) {                       // 57344 weight elems, 4 per thread
    int i4 = i * 4;
    float4 v;
    if (i4 < 8192)       v = *(const float4*)(w1 + i4);
    else if (i4 < 24576) v = *(const float4*)(m1 + i4 - 8192);
    else if (i4 < 40960) v = *(const float4*)(m2 + i4 - 24576);
    else                 v = *(const float4*)(m3 + i4 - 40960);
    ushort2 lo = { f2bf(v.x), f2bf(v.y) };
    ushort2 hi = { f2bf(v.z), f2bf(v.w) };
    *(ushort2*)(wb + i4) = lo;
    *(ushort2*)(wb + i4 + 2) = hi;
  }
  if (i < NN * CO / 4) {
    float4 v = *(const float4*)(u0 + i * 4);
    ushort2 lo = { f2bf(v.x), f2bf(v.y) };
    ushort2 hi = { f2bf(v.z), f2bf(v.w) };
    *(ushort2*)(ub + i * 4) = lo;
    *(ushort2*)(ub + i * 4 + 2) = hi;
  }
}

// ---------------- CSR gather (segment_sum), bf16 ----------------
// One node per 16-lane group, 4-deep staged loads (round-8 verified config).
// Both deeper ILP (round 12) and wave reorg (round 7) were null -> gather is
// at the memory system's random-read throughput limit.
__global__ __launch_bounds__(256) void k_gather(const int* __restrict__ row_off,
    const int* __restrict__ ssrc, const unsigned short* __restrict__ ubf,
    unsigned short* __restrict__ agg) {
  int wave = threadIdx.x >> 6, lane = threadIdx.x & 63;
  int g = lane >> 4, c = lane & 15;
  int node = blockIdx.x * 16 + wave * 4 + g;
  int gl = g << 4;                      // group's base lane
  int beg = row_off[node], end = row_off[node + 1];
  float a[8];
#pragma unroll
  for (int i = 0; i < 8; ++i) a[i] = 0.f;

#define ADD8(r) { a[0] += bf2f_lo(r.x); a[1] += bf2f_hi(r.x); \
                  a[2] += bf2f_lo(r.y); a[3] += bf2f_hi(r.y); \
                  a[4] += bf2f_lo(r.z); a[5] += bf2f_hi(r.z); \
                  a[6] += bf2f_lo(r.w); a[7] += bf2f_hi(r.w); }

  for (int base = beg; base < end; base += 16) {
    int e = base + c;
    int sid = (e < end) ? ssrc[e] : 0;  // 16 edges, 64B coalesced per group
    int cnt = min(16, end - base);
    int j = 0;
    for (; j + 4 <= cnt; j += 4) {
      int s0 = __shfl(sid, gl + j + 0);
      int s1 = __shfl(sid, gl + j + 1);
      int s2 = __shfl(sid, gl + j + 2);
      int s3 = __shfl(sid, gl + j + 3);
      uint4 r0 = *(const uint4*)(ubf + (size_t)s0 * CO + c * 8);
      uint4 r1 = *(const uint4*)(ubf + (size_t)s1 * CO + c * 8);
      uint4 r2 = *(const uint4*)(ubf + (size_t)s2 * CO + c * 8);
      uint4 r3 = *(const uint4*)(ubf + (size_t)s3 * CO + c * 8);
      ADD8(r0); ADD8(r1); ADD8(r2); ADD8(r3);
    }
    for (; j < cnt; ++j) {
      int s = __shfl(sid, gl + j);
      uint4 r = *(const uint4*)(ubf + (size_t)s * CO + c * 8);
      ADD8(r);
    }
  }
#undef ADD8
  uint4 o;
  o.x = pk2(a[0], a[1]); o.y = pk2(a[2], a[3]);
  o.z = pk2(a[4], a[5]); o.w = pk2(a[6], a[7]);
  *(uint4*)(agg + (size_t)node * CO + c * 8) = o;
}

// ---------------- xw = bf16(x @ w1^T + b1), f32 x read directly ----------------
__global__ __launch_bounds__(256) void k_xw(const float* __restrict__ X,
    const unsigned short* __restrict__ W, const float* __restrict__ bias,
    unsigned short* __restrict__ xwb) {
  int wave = threadIdx.x >> 6, lane = threadIdx.x & 63;
  int m = lane & 15, q = lane >> 4;
  int row0 = blockIdx.x * 64 + wave * 16;
  int arow = row0 + m; if (arow >= NN) arow = NN - 1;
  const float* Xr = X + (size_t)arow * CI;
  f32x4 acc[8];
#pragma unroll
  for (int tt = 0; tt < 8; ++tt) acc[tt] = (f32x4){0.f, 0.f, 0.f, 0.f};
#pragma unroll
  for (int ks = 0; ks < CI; ks += 32) {
    float4 f0 = *(const float4*)(Xr + ks + q * 8);
    float4 f1 = *(const float4*)(Xr + ks + q * 8 + 4);
    union { unsigned int u[4]; bf16x8 v; } cv;
    cv.u[0] = pk2(f0.x, f0.y); cv.u[1] = pk2(f0.z, f0.w);
    cv.u[2] = pk2(f1.x, f1.y); cv.u[3] = pk2(f1.z, f1.w);
    bf16x8 a = cv.v;
#pragma unroll
    for (int tt = 0; tt < 8; ++tt) {
      bf16x8 b = *(const bf16x8*)(W + (size_t)(tt * 16 + m) * CI + ks + q * 8);
      acc[tt] = __builtin_amdgcn_mfma_f32_16x16x32_bf16(a, b, acc[tt], 0, 0, 0);
    }
  }
#pragma unroll
  for (int tt = 0; tt < 8; ++tt) {
    int o = tt * 16 + m;
    float bv = bias[o];
#pragma unroll
    for (int r = 0; r < 4; ++r) {
      int node = row0 + q * 4 + r;
      if (node < NN) xwb[(size_t)node * CO + o] = f2bf(acc[tt][r] + bv);
    }
  }
}

// ---------------- fused 3-layer MLP + epilogue ----------------
// EXACT round-8 verified config (401.5us): 512 threads = 8 waves x 16 rows,
// SP=136 (stride >= 128 + pad; SP=120 corrupts — round 9), LDS 66KB ->
// 2 blocks/CU. 640t (round 11) and full fusion (round 6) both regressed.
__global__ __launch_bounds__(512, 4) void k_mlp(const unsigned short* __restrict__ agg,
    const unsigned short* __restrict__ W1, const unsigned short* __restrict__ W2,
    const unsigned short* __restrict__ W3,
    const float* __restrict__ b1, const float* __restrict__ b2, const float* __restrict__ b3,
    const unsigned short* __restrict__ xwb, unsigned short* __restrict__ uout) {
  constexpr int SP = 136;                 // 272 B act row stride, 16B-aligned
  __shared__ unsigned short lds[16384 + 8 * 16 * SP];   // 32KB weights + 34KB act
  unsigned short* wt = lds;
  int tid = threadIdx.x;
  int wave = tid >> 6, lane = tid & 63;
  int m = lane & 15, q = lane >> 4;
  int row0 = blockIdx.x * 128 + wave * 16;
  unsigned short* L = lds + 16384 + wave * 16 * SP;
  int ar = row0 + m; if (ar >= NN) ar = NN - 1;
  const unsigned short* Ap = agg + (size_t)ar * CO;

  uint4 wreg[4];
  const int trb = (tid >> 4) & 7;
  const int tc  = tid & 15;
  const int ldst0 = (tid >> 4) * 128 + ((tc ^ trb) << 3);   // shorts, + j*4096
  auto stage_load = [&](const unsigned short* W) {
#pragma unroll
    for (int j = 0; j < 4; ++j)
      wreg[j] = *(const uint4*)(W + ((j * 512 + tid) << 3));
  };
  auto stage_write = [&]() {
#pragma unroll
    for (int j = 0; j < 4; ++j)
      *(uint4*)(wt + ldst0 + j * 4096) = wreg[j];
  };
  auto bfrag = [&](int t, int ks) -> bf16x8 {
    int ch = (ks >> 3) + q;
    return *(const bf16x8*)(wt + (t * 16 + m) * 128 + ((ch ^ (m & 7)) << 3));
  };

  stage_load(W1);
  bf16x8 ar4[4];
#pragma unroll
  for (int k4 = 0; k4 < 4; ++k4) ar4[k4] = *(const bf16x8*)(Ap + k4 * 32 + q * 8);
  stage_write();

  f32x4 acc[8];
#pragma unroll
  for (int t = 0; t < 8; ++t) acc[t] = (f32x4){0.f, 0.f, 0.f, 0.f};
  __syncthreads();

  // ---- layer 1 ----
#pragma unroll
  for (int k4 = 0; k4 < 4; ++k4) {
#pragma unroll
    for (int t = 0; t < 8; ++t) {
      bf16x8 b = bfrag(t, k4 * 32);
      acc[t] = __builtin_amdgcn_mfma_f32_16x16x32_bf16(ar4[k4], b, acc[t], 0, 0, 0);
    }
  }
  stage_load(W2);
#pragma unroll
  for (int t = 0; t < 8; ++t) {
    float bv = b1[t * 16 + m];
#pragma unroll
    for (int r = 0; r < 4; ++r)
      L[(q * 4 + r) * SP + t * 16 + m] = f2bf(fmaxf(acc[t][r] + bv, 0.f));
  }
  __syncthreads();
  stage_write();
#pragma unroll
  for (int t = 0; t < 8; ++t) acc[t] = (f32x4){0.f, 0.f, 0.f, 0.f};
  __syncthreads();

  // ---- layer 2 ----
#pragma unroll
  for (int ks = 0; ks < CO; ks += 32) {
    bf16x8 a = *(const bf16x8*)(L + m * SP + ks + q * 8);
#pragma unroll
    for (int t = 0; t < 8; ++t) {
      bf16x8 b = bfrag(t, ks);
      acc[t] = __builtin_amdgcn_mfma_f32_16x16x32_bf16(a, b, acc[t], 0, 0, 0);
    }
  }
  stage_load(W3);
#pragma unroll
  for (int t = 0; t < 8; ++t) {
    float bv = b2[t * 16 + m];
#pragma unroll
    for (int r = 0; r < 4; ++r)
      L[(q * 4 + r) * SP + t * 16 + m] = f2bf(fmaxf(acc[t][r] + bv, 0.f));
  }
  __syncthreads();
  stage_write();
#pragma unroll
  for (int t = 0; t < 8; ++t) acc[t] = (f32x4){0.f, 0.f, 0.f, 0.f};
  __syncthreads();

  // ---- layer 3 ----
#pragma unroll
  for (int ks = 0; ks < CO; ks += 32) {
    bf16x8 a = *(const bf16x8*)(L + m * SP + ks + q * 8);
#pragma unroll
    for (int t = 0; t < 8; ++t) {
      bf16x8 b = bfrag(t, ks);
      acc[t] = __builtin_amdgcn_mfma_f32_16x16x32_bf16(a, b, acc[t], 0, 0, 0);
    }
  }
#pragma unroll
  for (int t = 0; t < 8; ++t) {
    float bv = b3[t * 16 + m];
#pragma unroll
    for (int r = 0; r < 4; ++r) {
      float v = acc[t][r] + bv;
      float e = __expf(2.f * v);
      v = 1.f - 2.f / (e + 1.f);        // tanh
      L[(q * 4 + r) * SP + t * 16 + m] = f2bf(v);
    }
  }
  int ln = lane >> 2, lc = lane & 3;
  int gnode = row0 + ln;
  if (gnode < NN) {
    const unsigned short* xr = xwb + (size_t)gnode * CO;
    unsigned short* ur = uout + (size_t)gnode * CO;
#pragma unroll
    for (int rnd = 0; rnd < 4; ++rnd) {
      int ch = (rnd * 4 + lc) * 8;
      uint4 h = *(const uint4*)(L + ln * SP + ch);
      uint4 xv = *(const uint4*)(xr + ch);
      uint4 o;
      o.x = pk2(fmaxf(bf2f_lo(h.x) + bf2f_lo(xv.x), 0.f), fmaxf(bf2f_hi(h.x) + bf2f_hi(xv.x), 0.f));
      o.y = pk2(fmaxf(bf2f_lo(h.y) + bf2f_lo(xv.y), 0.f), fmaxf(bf2f_hi(h.y) + bf2f_hi(xv.y), 0.f));
      o.z = pk2(fmaxf(bf2f_lo(h.z) + bf2f_lo(xv.z), 0.f), fmaxf(bf2f_hi(h.z) + bf2f_hi(xv.z), 0.f));
      o.w = pk2(fmaxf(bf2f_lo(h.w) + bf2f_lo(xv.w), 0.f), fmaxf(bf2f_hi(h.w) + bf2f_hi(xv.w), 0.f));
      *(uint4*)(ur + ch) = o;
    }
  }
}

// ---------------- final readout (k_final folded in via last-block) ----------------
__global__ __launch_bounds__(256) void k_reduce(const unsigned short* __restrict__ u,
                                                float* __restrict__ g,
                                                const float* __restrict__ w2,
                                                const float* __restrict__ b2,
                                                float* __restrict__ outp,
                                                int* __restrict__ done) {
  int ch2 = threadIdx.x & 63;
  int sub = threadIdx.x >> 6;
  float a0 = 0.f, a1 = 0.f;
  for (int n = blockIdx.x * 4 + sub; n < NN; n += gridDim.x * 4) {
    unsigned int p = *(const unsigned int*)(u + (size_t)n * CO + ch2 * 2);
    a0 += bf2f_lo(p); a1 += bf2f_hi(p);
  }
  __shared__ float s0[256], s1[256];
  s0[threadIdx.x] = a0; s1[threadIdx.x] = a1;
  __syncthreads();
  if (sub == 0) {
    a0 = s0[ch2] + s0[64 + ch2] + s0[128 + ch2] + s0[192 + ch2];
    a1 = s1[ch2] + s1[64 + ch2] + s1[128 + ch2] + s1[192 + ch2];
    atomicAdd(&g[ch2 * 2], a0);
    atomicAdd(&g[ch2 * 2 + 1], a1);
  }
  // last block computes the final 128x128 matvec (others exit -> no deadlock)
  __threadfence();
  __syncthreads();
  __shared__ int lastblk;
  if (threadIdx.x == 0) lastblk = (atomicAdd(done, 1) == (int)gridDim.x - 1);
  __syncthreads();
  if (!lastblk) return;
  __threadfence();
  __shared__ float sg[128];
  if (threadIdx.x < 128) sg[threadIdx.x] = atomicAdd(&g[threadIdx.x], 0.f);  // coherent read
  __syncthreads();
  int j = threadIdx.x;
  if (j < 128) {
    float acc = b2[j];
    for (int c = 0; c < 128; ++c) acc += sg[c] * w2[j * 128 + c];
    outp[j] = acc;
  }
}

extern "C" void kernel_launch(void* const* d_in, const int* in_sizes, int n_in,
                              void* d_out, int out_size, void* d_ws, size_t ws_size,
                              hipStream_t stream) {
  (void)in_sizes; (void)n_in; (void)out_size; (void)ws_size;
  const float* x   = (const float*)d_in[0];
  const float* u0  = (const float*)d_in[1];
  const int*   ei  = (const int*)d_in[2];
  const float* w1W = (const float*)d_in[3];
  const float* w1b = (const float*)d_in[4];
  const float* m1W = (const float*)d_in[5];
  const float* m1b = (const float*)d_in[6];
  const float* m2W = (const float*)d_in[7];
  const float* m2b = (const float*)d_in[8];
  const float* m3W = (const float*)d_in[9];
  const float* m3b = (const float*)d_in[10];
  const float* w2W = (const float*)d_in[11];
  const float* w2b = (const float*)d_in[12];
  const int* esrc = ei;
  const int* edst = ei + NE;

  char* p = (char*)d_ws;
  auto carve = [&](size_t bytes) { char* r = p; p += (bytes + 255) & ~(size_t)255; return r; };
  unsigned short* xwb     = (unsigned short*)carve((size_t)NN * CO * 2);
  unsigned short* ubf     = (unsigned short*)carve((size_t)NN * CO * 2);
  unsigned short* agg     = (unsigned short*)carve((size_t)NN * CO * 2);
  unsigned short* wbf     = (unsigned short*)carve((size_t)57344 * 2);
  int*            row_off = (int*)carve((size_t)(NN + 1) * 4);
  int*            ssrc    = (int*)carve((size_t)NE * 4);
  unsigned*       pairs   = (unsigned*)carve((size_t)NE * 4);
  int*            bkt_off = (int*)carve((size_t)(NB + 1) * 4);
  int*            bkt_cur = (int*)carve((size_t)NB * 4);
  // contiguous zero region: bkt_cnt (784->1024) + g (512->512) + done (8->256)
  char*           zbase   = carve((size_t)NB * 4);          // bkt_cnt
  int*            bkt_cnt = (int*)zbase;
  float*          g       = (float*)carve(128 * 4);         // = zbase + 1024
  int*            done    = (int*)carve(8);                 // = zbase + 1536

  hipMemsetAsync(zbase, 0, 1792, stream);   // bkt_cnt + g + done counters

  // binned CSR build (3 kernels; bscan folded into bhist)
  k_bhist<<<NCH, 256, 0, stream>>>(edst, bkt_cnt, bkt_off, bkt_cur, done);
  k_bin<<<NCH, 256, 0, stream>>>(esrc, edst, bkt_cur, pairs);
  k_fillB<<<NB, 256, 0, stream>>>(pairs, bkt_off, row_off, ssrc);

  // fused weight+u0 bf16 conversion (1 launch)
  k_cvt<<<(NN * CO / 4 + 255) / 256, 256, 0, stream>>>(w1W, m1W, m2W, m3W, wbf, u0, ubf);

  k_xw<<<(NN + 63) / 64, 256, 0, stream>>>(x, wbf, w1b, xwb);

  const unsigned short* Wm1 = wbf + 8192;
  const unsigned short* Wm2 = wbf + 8192 + 16384;
  const unsigned short* Wm3 = wbf + 8192 + 2 * 16384;
  const int GM = (NN + 127) / 128;
  for (int it = 0; it < 4; ++it) {
    k_gather<<<NN / 16, 256, 0, stream>>>(row_off, ssrc, ubf, agg);
    k_mlp<<<GM, 512, 0, stream>>>(agg, Wm1, Wm2, Wm3, m1b, m2b, m3b, xwb, ubf);
  }

  // reduce + final matvec (1 launch; final folded via last-block)
  k_reduce<<<256, 256, 0, stream>>>(ubf, g, w2W, w2b, (float*)d_out, done + 1);
}

// Round 15
// 398.975 us; speedup vs baseline: 1.0455x; 1.0455x over previous
//
#include <hip/hip_runtime.h>
#include <hip/hip_bf16.h>

#define NN 50000
#define NE 800000
#define CI 64
#define CO 128
#define NB 196     // ceil(NN/256) buckets of 256 nodes
#define CHUNK 2048 // edges per bin block
#define NCH 391    // ceil(NE/CHUNK)

typedef __attribute__((ext_vector_type(8))) short bf16x8;
typedef __attribute__((ext_vector_type(4))) float f32x4;

__device__ __forceinline__ unsigned short f2bf(float f) {
  unsigned int u = __float_as_uint(f);
  u += 0x7fffu + ((u >> 16) & 1u);   // RNE; inputs are finite
  return (unsigned short)(u >> 16);
}
__device__ __forceinline__ float bf2f_lo(unsigned int p) { return __uint_as_float(p << 16); }
__device__ __forceinline__ float bf2f_hi(unsigned int p) { return __uint_as_float(p & 0xffff0000u); }
__device__ __forceinline__ unsigned int pk2(float lo, float hi) {
  return ((unsigned int)f2bf(hi) << 16) | (unsigned int)f2bf(lo);
}

// ---------------- binned CSR build (round-5 verified; consolidated round-8) ----------------
// Round-13 lesson: folding bscan/final into producers via last-block pattern
// REGRESSED +13us (cross-XCD __threadfence + hot-line atomics). Keep separate.
__global__ __launch_bounds__(256) void k_bhist(const int* __restrict__ dst,
                                               int* __restrict__ bcnt) {
  __shared__ int lc[NB];
  int tid = threadIdx.x;
  for (int t = tid; t < NB; t += 256) lc[t] = 0;
  __syncthreads();
  int base = blockIdx.x * CHUNK;
#pragma unroll
  for (int i = 0; i < 8; ++i) {
    int idx = base + i * 256 + tid;
    if (idx < NE) atomicAdd(&lc[dst[idx] >> 8], 1);
  }
  __syncthreads();
  for (int t = tid; t < NB; t += 256) if (lc[t]) atomicAdd(&bcnt[t], lc[t]);
}

__global__ __launch_bounds__(256) void k_bscan(const int* __restrict__ bcnt,
                                               int* __restrict__ bkt_off,
                                               int* __restrict__ bkt_cur) {
  __shared__ int s[256];
  int t = threadIdx.x;
  int v = (t < NB) ? bcnt[t] : 0;
  s[t] = v;
  __syncthreads();
  for (int off = 1; off < 256; off <<= 1) {
    int x = (t >= off) ? s[t - off] : 0;
    __syncthreads();
    s[t] += x;
    __syncthreads();
  }
  if (t < NB) { int e = s[t] - v; bkt_off[t] = e; bkt_cur[t] = e; }
  if (t == 0) bkt_off[NB] = NE;
}

__global__ __launch_bounds__(256) void k_bin(const int* __restrict__ src,
                                             const int* __restrict__ dst,
                                             int* __restrict__ bkt_cur,
                                             uint2* __restrict__ pairs) {
  __shared__ int lcnt[NB];
  __shared__ int lbase[NB];
  int tid = threadIdx.x;
  for (int t = tid; t < NB; t += 256) lcnt[t] = 0;
  __syncthreads();
  int base = blockIdx.x * CHUNK;
  int ds[8], sr[8], rk[8];
#pragma unroll
  for (int i = 0; i < 8; ++i) {
    int idx = base + i * 256 + tid;
    if (idx < NE) {
      ds[i] = dst[idx]; sr[i] = src[idx];
      rk[i] = atomicAdd(&lcnt[ds[i] >> 8], 1);
    } else ds[i] = -1;
  }
  __syncthreads();
  for (int t = tid; t < NB; t += 256)
    lbase[t] = lcnt[t] ? atomicAdd(&bkt_cur[t], lcnt[t]) : 0;
  __syncthreads();
#pragma unroll
  for (int i = 0; i < 8; ++i) {
    if (ds[i] >= 0) {
      uint2 pr; pr.x = (unsigned)sr[i]; pr.y = (unsigned)ds[i];
      pairs[lbase[ds[i] >> 8] + rk[i]] = pr;
    }
  }
}

// Merged: per-bucket histogram -> LDS scan -> row_off -> ssrc fill.
__global__ __launch_bounds__(256) void k_fillB(const uint2* __restrict__ pairs,
                                               const int* __restrict__ bkt_off,
                                               int* __restrict__ row_off,
                                               int* __restrict__ ssrc) {
  __shared__ int lc[256];
  __shared__ int ls[256];
  int t = threadIdx.x, b = blockIdx.x;
  lc[t] = 0;
  __syncthreads();
  int beg = bkt_off[b], end = bkt_off[b + 1];
  for (int i = beg + t; i < end; i += 256)
    atomicAdd(&lc[pairs[i].y & 255], 1);
  __syncthreads();
  int v = lc[t];
  ls[t] = v;
  __syncthreads();
  for (int off = 1; off < 256; off <<= 1) {
    int x = (t >= off) ? ls[t - off] : 0;
    __syncthreads();
    ls[t] += x;
    __syncthreads();
  }
  int excl = ls[t] - v;
  int node = (b << 8) + t;
  if (node < NN) row_off[node] = beg + excl;
  if (b == 0 && t == 0) row_off[NN] = NE;
  lc[t] = beg + excl;          // reuse as global-position cursor
  __syncthreads();
  for (int i = beg + t; i < end; i += 256) {
    uint2 e = pairs[i];
    int pos = atomicAdd(&lc[e.y & 255], 1);
    ssrc[pos] = (int)e.x;
  }
}

// ---------------- bf16 conversions ----------------
__global__ void k_cvt_w(const float* __restrict__ w1, const float* __restrict__ m1,
                        const float* __restrict__ m2, const float* __restrict__ m3,
                        unsigned short* __restrict__ o) {
  int i = blockIdx.x * blockDim.x + threadIdx.x;
  if (i >= 57344) return;
  float v;
  if (i < 8192) v = w1[i];
  else if (i < 24576) v = m1[i - 8192];
  else if (i < 40960) v = m2[i - 24576];
  else v = m3[i - 40960];
  o[i] = f2bf(v);
}

__global__ void k_cvt4(const float* __restrict__ in, unsigned short* __restrict__ out, int n4) {
  int i = blockIdx.x * blockDim.x + threadIdx.x;
  if (i >= n4) return;
  float4 v = *(const float4*)(in + i * 4);
  ushort2 lo = { f2bf(v.x), f2bf(v.y) };
  ushort2 hi = { f2bf(v.z), f2bf(v.w) };
  *(ushort2*)(out + i * 4) = lo;
  *(ushort2*)(out + i * 4 + 2) = hi;
}

// ---------------- CSR gather (segment_sum), bf16 ----------------
// One node per 16-lane group, 4-deep staged loads. At the memory system's
// random-read limit: wave reorg (round 7) and 8-deep ILP (round 12) both null.
__global__ __launch_bounds__(256) void k_gather(const int* __restrict__ row_off,
    const int* __restrict__ ssrc, const unsigned short* __restrict__ ubf,
    unsigned short* __restrict__ agg) {
  int wave = threadIdx.x >> 6, lane = threadIdx.x & 63;
  int g = lane >> 4, c = lane & 15;
  int node = blockIdx.x * 16 + wave * 4 + g;
  int gl = g << 4;                      // group's base lane
  int beg = row_off[node], end = row_off[node + 1];
  float a[8];
#pragma unroll
  for (int i = 0; i < 8; ++i) a[i] = 0.f;

#define ADD8(r) { a[0] += bf2f_lo(r.x); a[1] += bf2f_hi(r.x); \
                  a[2] += bf2f_lo(r.y); a[3] += bf2f_hi(r.y); \
                  a[4] += bf2f_lo(r.z); a[5] += bf2f_hi(r.z); \
                  a[6] += bf2f_lo(r.w); a[7] += bf2f_hi(r.w); }

  for (int base = beg; base < end; base += 16) {
    int e = base + c;
    int sid = (e < end) ? ssrc[e] : 0;  // 16 edges, 64B coalesced per group
    int cnt = min(16, end - base);
    int j = 0;
    for (; j + 4 <= cnt; j += 4) {
      int s0 = __shfl(sid, gl + j + 0);
      int s1 = __shfl(sid, gl + j + 1);
      int s2 = __shfl(sid, gl + j + 2);
      int s3 = __shfl(sid, gl + j + 3);
      uint4 r0 = *(const uint4*)(ubf + (size_t)s0 * CO + c * 8);
      uint4 r1 = *(const uint4*)(ubf + (size_t)s1 * CO + c * 8);
      uint4 r2 = *(const uint4*)(ubf + (size_t)s2 * CO + c * 8);
      uint4 r3 = *(const uint4*)(ubf + (size_t)s3 * CO + c * 8);
      ADD8(r0); ADD8(r1); ADD8(r2); ADD8(r3);
    }
    for (; j < cnt; ++j) {
      int s = __shfl(sid, gl + j);
      uint4 r = *(const uint4*)(ubf + (size_t)s * CO + c * 8);
      ADD8(r);
    }
  }
#undef ADD8
  uint4 o;
  o.x = pk2(a[0], a[1]); o.y = pk2(a[2], a[3]);
  o.z = pk2(a[4], a[5]); o.w = pk2(a[6], a[7]);
  *(uint4*)(agg + (size_t)node * CO + c * 8) = o;
}

// ---------------- xw = bf16(x @ w1^T + b1), f32 x read directly ----------------
__global__ __launch_bounds__(256) void k_xw(const float* __restrict__ X,
    const unsigned short* __restrict__ W, const float* __restrict__ bias,
    unsigned short* __restrict__ xwb) {
  int wave = threadIdx.x >> 6, lane = threadIdx.x & 63;
  int m = lane & 15, q = lane >> 4;
  int row0 = blockIdx.x * 64 + wave * 16;
  int arow = row0 + m; if (arow >= NN) arow = NN - 1;
  const float* Xr = X + (size_t)arow * CI;
  f32x4 acc[8];
#pragma unroll
  for (int tt = 0; tt < 8; ++tt) acc[tt] = (f32x4){0.f, 0.f, 0.f, 0.f};
#pragma unroll
  for (int ks = 0; ks < CI; ks += 32) {
    float4 f0 = *(const float4*)(Xr + ks + q * 8);
    float4 f1 = *(const float4*)(Xr + ks + q * 8 + 4);
    union { unsigned int u[4]; bf16x8 v; } cv;
    cv.u[0] = pk2(f0.x, f0.y); cv.u[1] = pk2(f0.z, f0.w);
    cv.u[2] = pk2(f1.x, f1.y); cv.u[3] = pk2(f1.z, f1.w);
    bf16x8 a = cv.v;
#pragma unroll
    for (int tt = 0; tt < 8; ++tt) {
      bf16x8 b = *(const bf16x8*)(W + (size_t)(tt * 16 + m) * CI + ks + q * 8);
      acc[tt] = __builtin_amdgcn_mfma_f32_16x16x32_bf16(a, b, acc[tt], 0, 0, 0);
    }
  }
#pragma unroll
  for (int tt = 0; tt < 8; ++tt) {
    int o = tt * 16 + m;
    float bv = bias[o];
#pragma unroll
    for (int r = 0; r < 4; ++r) {
      int node = row0 + q * 4 + r;
      if (node < NN) xwb[(size_t)node * CO + o] = f2bf(acc[tt][r] + bv);
    }
  }
}

// ---------------- fused 3-layer MLP + epilogue ----------------
// Verified optimum (round 8, 401.5us): 512 threads = 8 waves x 16 rows,
// SP=136 (stride >= 128 + pad; SP=120 corrupts — round 9), LDS 66KB ->
// 2 blocks/CU. Store geometry: ln=lane>>2 (0..15 = rows/wave), lc=lane&3,
// 4 rounds — round-14's NaN was ln=lane>>1 (0..31) overrunning the 16-row
// wave tile. INVARIANT: ln range == rows/wave.
__global__ __launch_bounds__(512, 4) void k_mlp(const unsigned short* __restrict__ agg,
    const unsigned short* __restrict__ W1, const unsigned short* __restrict__ W2,
    const unsigned short* __restrict__ W3,
    const float* __restrict__ b1, const float* __restrict__ b2, const float* __restrict__ b3,
    const unsigned short* __restrict__ xwb, unsigned short* __restrict__ uout) {
  constexpr int SP = 136;                 // 272 B act row stride, 16B-aligned
  __shared__ unsigned short lds[16384 + 8 * 16 * SP];   // 32KB weights + 34KB act
  unsigned short* wt = lds;
  int tid = threadIdx.x;
  int wave = tid >> 6, lane = tid & 63;
  int m = lane & 15, q = lane >> 4;
  int row0 = blockIdx.x * 128 + wave * 16;
  unsigned short* L = lds + 16384 + wave * 16 * SP;
  int ar = row0 + m; if (ar >= NN) ar = NN - 1;
  const unsigned short* Ap = agg + (size_t)ar * CO;

  uint4 wreg[4];
  const int trb = (tid >> 4) & 7;
  const int tc  = tid & 15;
  const int ldst0 = (tid >> 4) * 128 + ((tc ^ trb) << 3);   // shorts, + j*4096
  auto stage_load = [&](const unsigned short* W) {
#pragma unroll
    for (int j = 0; j < 4; ++j)
      wreg[j] = *(const uint4*)(W + ((j * 512 + tid) << 3));
  };
  auto stage_write = [&]() {
#pragma unroll
    for (int j = 0; j < 4; ++j)
      *(uint4*)(wt + ldst0 + j * 4096) = wreg[j];
  };
  auto bfrag = [&](int t, int ks) -> bf16x8 {
    int ch = (ks >> 3) + q;
    return *(const bf16x8*)(wt + (t * 16 + m) * 128 + ((ch ^ (m & 7)) << 3));
  };

  stage_load(W1);
  bf16x8 ar4[4];
#pragma unroll
  for (int k4 = 0; k4 < 4; ++k4) ar4[k4] = *(const bf16x8*)(Ap + k4 * 32 + q * 8);
  stage_write();

  f32x4 acc[8];
#pragma unroll
  for (int t = 0; t < 8; ++t) acc[t] = (f32x4){0.f, 0.f, 0.f, 0.f};
  __syncthreads();

  // ---- layer 1 ----
#pragma unroll
  for (int k4 = 0; k4 < 4; ++k4) {
#pragma unroll
    for (int t = 0; t < 8; ++t) {
      bf16x8 b = bfrag(t, k4 * 32);
      acc[t] = __builtin_amdgcn_mfma_f32_16x16x32_bf16(ar4[k4], b, acc[t], 0, 0, 0);
    }
  }
  stage_load(W2);
#pragma unroll
  for (int t = 0; t < 8; ++t) {
    float bv = b1[t * 16 + m];
#pragma unroll
    for (int r = 0; r < 4; ++r)
      L[(q * 4 + r) * SP + t * 16 + m] = f2bf(fmaxf(acc[t][r] + bv, 0.f));
  }
  __syncthreads();
  stage_write();
#pragma unroll
  for (int t = 0; t < 8; ++t) acc[t] = (f32x4){0.f, 0.f, 0.f, 0.f};
  __syncthreads();

  // ---- layer 2 ----
#pragma unroll
  for (int ks = 0; ks < CO; ks += 32) {
    bf16x8 a = *(const bf16x8*)(L + m * SP + ks + q * 8);
#pragma unroll
    for (int t = 0; t < 8; ++t) {
      bf16x8 b = bfrag(t, ks);
      acc[t] = __builtin_amdgcn_mfma_f32_16x16x32_bf16(a, b, acc[t], 0, 0, 0);
    }
  }
  stage_load(W3);
#pragma unroll
  for (int t = 0; t < 8; ++t) {
    float bv = b2[t * 16 + m];
#pragma unroll
    for (int r = 0; r < 4; ++r)
      L[(q * 4 + r) * SP + t * 16 + m] = f2bf(fmaxf(acc[t][r] + bv, 0.f));
  }
  __syncthreads();
  stage_write();
#pragma unroll
  for (int t = 0; t < 8; ++t) acc[t] = (f32x4){0.f, 0.f, 0.f, 0.f};
  __syncthreads();

  // ---- layer 3 ----
#pragma unroll
  for (int ks = 0; ks < CO; ks += 32) {
    bf16x8 a = *(const bf16x8*)(L + m * SP + ks + q * 8);
#pragma unroll
    for (int t = 0; t < 8; ++t) {
      bf16x8 b = bfrag(t, ks);
      acc[t] = __builtin_amdgcn_mfma_f32_16x16x32_bf16(a, b, acc[t], 0, 0, 0);
    }
  }
#pragma unroll
  for (int t = 0; t < 8; ++t) {
    float bv = b3[t * 16 + m];
#pragma unroll
    for (int r = 0; r < 4; ++r) {
      float v = acc[t][r] + bv;
      float e = __expf(2.f * v);
      v = 1.f - 2.f / (e + 1.f);        // tanh
      L[(q * 4 + r) * SP + t * 16 + m] = f2bf(v);
    }
  }
  // fused store: 16 rows x 16 chunks(16B) = 256 chunks; 64 lanes x 4 rounds
  int ln = lane >> 2, lc = lane & 3;
  int gnode = row0 + ln;
  if (gnode < NN) {
    const unsigned short* xr = xwb + (size_t)gnode * CO;
    unsigned short* ur = uout + (size_t)gnode * CO;
#pragma unroll
    for (int rnd = 0; rnd < 4; ++rnd) {
      int ch = (rnd * 4 + lc) * 8;
      uint4 h = *(const uint4*)(L + ln * SP + ch);
      uint4 xv = *(const uint4*)(xr + ch);
      uint4 o;
      o.x = pk2(fmaxf(bf2f_lo(h.x) + bf2f_lo(xv.x), 0.f), fmaxf(bf2f_hi(h.x) + bf2f_hi(xv.x), 0.f));
      o.y = pk2(fmaxf(bf2f_lo(h.y) + bf2f_lo(xv.y), 0.f), fmaxf(bf2f_hi(h.y) + bf2f_hi(xv.y), 0.f));
      o.z = pk2(fmaxf(bf2f_lo(h.z) + bf2f_lo(xv.z), 0.f), fmaxf(bf2f_hi(h.z) + bf2f_hi(xv.z), 0.f));
      o.w = pk2(fmaxf(bf2f_lo(h.w) + bf2f_lo(xv.w), 0.f), fmaxf(bf2f_hi(h.w) + bf2f_hi(xv.w), 0.f));
      *(uint4*)(ur + ch) = o;
    }
  }
}

// ---------------- final readout ----------------
__global__ __launch_bounds__(256) void k_reduce(const unsigned short* __restrict__ u,
                                                float* __restrict__ g) {
  int ch2 = threadIdx.x & 63;
  int sub = threadIdx.x >> 6;
  float a0 = 0.f, a1 = 0.f;
  for (int n = blockIdx.x * 4 + sub; n < NN; n += gridDim.x * 4) {
    unsigned int p = *(const unsigned int*)(u + (size_t)n * CO + ch2 * 2);
    a0 += bf2f_lo(p); a1 += bf2f_hi(p);
  }
  __shared__ float s0[256], s1[256];
  s0[threadIdx.x] = a0; s1[threadIdx.x] = a1;
  __syncthreads();
  if (sub == 0) {
    a0 = s0[ch2] + s0[64 + ch2] + s0[128 + ch2] + s0[192 + ch2];
    a1 = s1[ch2] + s1[64 + ch2] + s1[128 + ch2] + s1[192 + ch2];
    atomicAdd(&g[ch2 * 2], a0);
    atomicAdd(&g[ch2 * 2 + 1], a1);
  }
}

__global__ void k_final(const float* __restrict__ g, const float* __restrict__ w2,
                        const float* __restrict__ b2, float* __restrict__ outp) {
  __shared__ float sg[128];
  if (threadIdx.x < 128) sg[threadIdx.x] = g[threadIdx.x];
  __syncthreads();
  int j = threadIdx.x;
  if (j < 128) {
    float acc = b2[j];
    for (int c = 0; c < 128; ++c) acc += sg[c] * w2[j * 128 + c];
    outp[j] = acc;
  }
}

extern "C" void kernel_launch(void* const* d_in, const int* in_sizes, int n_in,
                              void* d_out, int out_size, void* d_ws, size_t ws_size,
                              hipStream_t stream) {
  (void)in_sizes; (void)n_in; (void)out_size; (void)ws_size;
  const float* x   = (const float*)d_in[0];
  const float* u0  = (const float*)d_in[1];
  const int*   ei  = (const int*)d_in[2];
  const float* w1W = (const float*)d_in[3];
  const float* w1b = (const float*)d_in[4];
  const float* m1W = (const float*)d_in[5];
  const float* m1b = (const float*)d_in[6];
  const float* m2W = (const float*)d_in[7];
  const float* m2b = (const float*)d_in[8];
  const float* m3W = (const float*)d_in[9];
  const float* m3b = (const float*)d_in[10];
  const float* w2W = (const float*)d_in[11];
  const float* w2b = (const float*)d_in[12];
  const int* esrc = ei;
  const int* edst = ei + NE;

  char* p = (char*)d_ws;
  auto carve = [&](size_t bytes) { char* r = p; p += (bytes + 255) & ~(size_t)255; return r; };
  unsigned short* xwb     = (unsigned short*)carve((size_t)NN * CO * 2);
  unsigned short* ubf     = (unsigned short*)carve((size_t)NN * CO * 2);
  unsigned short* agg     = (unsigned short*)carve((size_t)NN * CO * 2);
  unsigned short* wbf     = (unsigned short*)carve((size_t)57344 * 2);
  int*            row_off = (int*)carve((size_t)(NN + 1) * 4);
  int*            ssrc    = (int*)carve((size_t)NE * 4);
  uint2*          pairs   = (uint2*)carve((size_t)NE * 8);
  int*            bkt_cnt = (int*)carve((size_t)NB * 4);
  int*            bkt_off = (int*)carve((size_t)(NB + 1) * 4);
  int*            bkt_cur = (int*)carve((size_t)NB * 4);
  float*          g       = (float*)carve(128 * 4);

  hipMemsetAsync(bkt_cnt, 0, (size_t)NB * 4, stream);
  hipMemsetAsync(g, 0, 128 * 4, stream);

  // binned CSR build (4 kernels)
  k_bhist<<<NCH, 256, 0, stream>>>(edst, bkt_cnt);
  k_bscan<<<1, 256, 0, stream>>>(bkt_cnt, bkt_off, bkt_cur);
  k_bin<<<NCH, 256, 0, stream>>>(esrc, edst, bkt_cur, pairs);
  k_fillB<<<NB, 256, 0, stream>>>(pairs, bkt_off, row_off, ssrc);

  k_cvt_w<<<(57344 + 255) / 256, 256, 0, stream>>>(w1W, m1W, m2W, m3W, wbf);
  k_cvt4<<<(NN * CO / 4 + 255) / 256, 256, 0, stream>>>(u0, ubf, NN * CO / 4);

  k_xw<<<(NN + 63) / 64, 256, 0, stream>>>(x, wbf, w1b, xwb);

  const unsigned short* Wm1 = wbf + 8192;
  const unsigned short* Wm2 = wbf + 8192 + 16384;
  const unsigned short* Wm3 = wbf + 8192 + 2 * 16384;
  const int GM = (NN + 127) / 128;
  for (int it = 0; it < 4; ++it) {
    k_gather<<<NN / 16, 256, 0, stream>>>(row_off, ssrc, ubf, agg);
    k_mlp<<<GM, 512, 0, stream>>>(agg, Wm1, Wm2, Wm3, m1b, m2b, m3b, xwb, ubf);
  }

  k_reduce<<<256, 256, 0, stream>>>(ubf, g);
  k_final<<<1, 128, 0, stream>>>(g, w2W, w2b, (float*)d_out);
}